// Round 1
// baseline (61363.470 us; speedup 1.0000x reference)
//
#include <hip/hip_runtime.h>
#include <hip/hip_cooperative_groups.h>

namespace cg = cooperative_groups;

#define B   1024
#define T   256
#define IN  128
#define H1  256
#define H2  256
#define H3  32
#define K1  (IN + H1)   // 384
#define K2  (H1 + H2)   // 512
#define K3  (H2 + H3)   // 288
#define NBLK 256
#define NTHR 512
#define EPS 1e-5f

// ws layout (float offsets)
#define WS_H1   0                        // [2][B*H1] double-buffered
#define WS_C1   (WS_H1 + 2 * B * H1)     // [B*H1]
#define WS_H2   (WS_C1 + B * H1)         // [2][B*H2]
#define WS_C2   (WS_H2 + 2 * B * H2)     // [B*H2]
#define WS_H3   (WS_C2 + B * H2)         // [2][B*H3]
#define WS_C3   (WS_H3 + 2 * B * H3)     // [B*H3]
#define WS_S1   (WS_C3 + B * H3)         // [H1][4][2] partial (sum,sumsq)
#define WS_S2   (WS_S1 + H1 * 4 * 2)     // [H2][4][2]
#define WS_S3   (WS_S2 + H2 * 4 * 2)     // [H3][8][2]

__device__ __forceinline__ float fsigmoid(float v) { return 1.f / (1.f + __expf(-v)); }
__device__ __forceinline__ float ftanh(float v)    { return 1.f - 2.f / (__expf(2.f * v) + 1.f); }

#define FMA4(acc_, av_, wv_) (acc_) += (av_).x*(wv_).x + (av_).y*(wv_).y + (av_).z*(wv_).z + (av_).w*(wv_).w

// BN3 + linear head + softmax for output column tout. Called by blocks 0..3 only.
__device__ __forceinline__ void head_pass(
    int blk, int tid, int tout,
    const float* __restrict__ h3s, const float* __restrict__ st3,
    const float* __restrict__ g3v, const float* __restrict__ b3v,
    const float* __restrict__ Wl,  const float* __restrict__ bl,
    const float* __restrict__ Wl2, const float* __restrict__ bl2,
    float* __restrict__ out, float* s_a3, float* s_d3)
{
    if (tid < H3) {
        float s = 0.f, sq = 0.f;
        #pragma unroll
        for (int p = 0; p < 8; ++p) {
            s  += st3[(tid * 8 + p) * 2 + 0];
            sq += st3[(tid * 8 + p) * 2 + 1];
        }
        const float mu  = s * (1.f / B);
        const float var = sq * (1.f / B) - mu * mu;
        const float a   = g3v[tid] * rsqrtf(var + EPS);
        s_a3[tid] = a;
        s_d3[tid] = b3v[tid] - mu * a;
    }
    __syncthreads();
    if (tid < 256) {
        const int b = blk * 256 + tid;
        float y0 = bl[0], y1 = bl[1];
        #pragma unroll
        for (int ch = 0; ch < H3; ++ch) {
            const float z = s_a3[ch] * h3s[(size_t)b * H3 + ch] + s_d3[ch];
            y0 += Wl[ch] * z;
            y1 += Wl[H3 + ch] * z;
        }
        y0 = fmaxf(y0, 0.f);
        y1 = fmaxf(y1, 0.f);
        const float u0 = Wl2[0] * y0 + Wl2[1] * y1 + bl2[0];
        const float u1 = Wl2[2] * y0 + Wl2[3] * y1 + bl2[1];
        const float m  = fmaxf(u0, u1);
        const float e0 = __expf(u0 - m), e1 = __expf(u1 - m);
        const float inv = 1.f / (e0 + e1);
        out[((size_t)b * T + tout) * 2 + 0] = e0 * inv;
        out[((size_t)b * T + tout) * 2 + 1] = e1 * inv;
    }
}

__global__ void __launch_bounds__(NTHR, 1) cryptonet_kernel(
    const float* __restrict__ x,
    const float* __restrict__ Wih1, const float* __restrict__ Whh1,
    const float* __restrict__ bih1, const float* __restrict__ bhh1,
    const float* __restrict__ g1v,  const float* __restrict__ b1v,
    const float* __restrict__ Wih2, const float* __restrict__ Whh2,
    const float* __restrict__ bih2, const float* __restrict__ bhh2,
    const float* __restrict__ g2v,  const float* __restrict__ b2v,
    const float* __restrict__ Wih3, const float* __restrict__ Whh3,
    const float* __restrict__ bih3, const float* __restrict__ bhh3,
    const float* __restrict__ g3v,  const float* __restrict__ b3v,
    const float* __restrict__ Wl,   const float* __restrict__ bl,
    const float* __restrict__ Wl2,  const float* __restrict__ bl2,
    float* __restrict__ out, float* __restrict__ ws)
{
    cg::grid_group grid = cg::this_grid();
    const int tid = threadIdx.x;
    const int blk = blockIdx.x;

    __shared__ float s_w[16 * K2];     // 32 KB: max of W1(24K)/W2(32K)/W3(4.5K) staging
    __shared__ float s_bias[16];
    __shared__ float s_a[H1], s_d[H1]; // folded BN scale/shift of previous layer
    __shared__ float s_a3[H3], s_d3[H3];
    __shared__ float s_red[16];

    float* h1buf = ws + WS_H1;
    float* c1    = ws + WS_C1;
    float* h2buf = ws + WS_H2;
    float* c2    = ws + WS_C2;
    float* h3buf = ws + WS_H3;
    float* c3    = ws + WS_C3;
    float* st1   = ws + WS_S1;
    float* st2   = ws + WS_S2;
    float* st3   = ws + WS_S3;

    // zero initial state (ws is poisoned 0xAA before every call)
    {
        const int gt = blk * NTHR + tid;
        const int gs = NBLK * NTHR;
        for (int i = gt; i < B * H1; i += gs) { h1buf[i] = 0.f; c1[i] = 0.f; }
        for (int i = gt; i < B * H2; i += gs) { h2buf[i] = 0.f; c2[i] = 0.f; }
        for (int i = gt; i < B * H3; i += gs) { h3buf[i] = 0.f; c3[i] = 0.f; }
    }
    grid.sync();

    // L1/L2 tiling: 64 channel-groups (4 ch) x 4 batch-groups (256 b)
    const int cgq = blk >> 2;          // 0..63
    const int bgq = blk & 3;           // 0..3
    const int ch0 = cgq * 4;
    const int chl = tid >> 7;          // 0..3 (2 waves per channel)
    const int bt  = tid & 127;         // 0..127
    const int bb  = bgq * 256 + bt;    // thread owns b = bb, bb+128

    for (int t = 0; t < T; ++t) {
        const float* h1p = h1buf + (t & 1) * (B * H1);
        float*       h1c = h1buf + ((t + 1) & 1) * (B * H1);
        const float* h2p = h2buf + (t & 1) * (B * H2);
        float*       h2c = h2buf + ((t + 1) & 1) * (B * H2);
        const float* h3p = h3buf + (t & 1) * (B * H3);
        float*       h3c = h3buf + ((t + 1) & 1) * (B * H3);

        // ================= Phase 1: head(t-1) + L1(t) =================
        if (blk < 4 && t > 0)
            head_pass(blk, tid, t - 1, h3p, st3, g3v, b3v, Wl, bl, Wl2, bl2, out, s_a3, s_d3);

        // stage W1 rows for our 4 channels (gate order i,f,g,o: row j = g*H1 + ch)
        for (int idx = tid; idx < 16 * K1; idx += NTHR) {
            const int ch  = idx / (4 * K1);
            const int rem = idx - ch * (4 * K1);
            const int g   = rem / K1;
            const int k   = rem - g * K1;
            const int j   = g * H1 + ch0 + ch;
            s_w[(ch * 4 + g) * K1 + k] = (k < IN) ? Wih1[j * IN + k] : Whh1[j * H1 + (k - IN)];
        }
        if (tid < 16) {
            const int j = (tid & 3) * H1 + ch0 + (tid >> 2);
            s_bias[tid] = bih1[j] + bhh1[j];
        }
        __syncthreads();

        {
            float acc[2][4];
            #pragma unroll
            for (int i = 0; i < 2; ++i)
                #pragma unroll
                for (int g = 0; g < 4; ++g) acc[i][g] = 0.f;

            const float* wb = &s_w[(chl * 4) * K1];
            const size_t xr0 = ((size_t)bb * T + t) * IN;
            const size_t xr1 = ((size_t)(bb + 128) * T + t) * IN;
            for (int k = 0; k < IN; k += 4) {
                const float4 w0 = *(const float4*)&wb[0 * K1 + k];
                const float4 w1 = *(const float4*)&wb[1 * K1 + k];
                const float4 w2 = *(const float4*)&wb[2 * K1 + k];
                const float4 w3 = *(const float4*)&wb[3 * K1 + k];
                const float4 a0 = *(const float4*)&x[xr0 + k];
                const float4 a1 = *(const float4*)&x[xr1 + k];
                FMA4(acc[0][0], a0, w0); FMA4(acc[0][1], a0, w1);
                FMA4(acc[0][2], a0, w2); FMA4(acc[0][3], a0, w3);
                FMA4(acc[1][0], a1, w0); FMA4(acc[1][1], a1, w1);
                FMA4(acc[1][2], a1, w2); FMA4(acc[1][3], a1, w3);
            }
            const size_t hr0 = (size_t)bb * H1;
            const size_t hr1 = (size_t)(bb + 128) * H1;
            for (int k = 0; k < H1; k += 4) {
                const float4 w0 = *(const float4*)&wb[0 * K1 + IN + k];
                const float4 w1 = *(const float4*)&wb[1 * K1 + IN + k];
                const float4 w2 = *(const float4*)&wb[2 * K1 + IN + k];
                const float4 w3 = *(const float4*)&wb[3 * K1 + IN + k];
                const float4 a0 = *(const float4*)&h1p[hr0 + k];
                const float4 a1 = *(const float4*)&h1p[hr1 + k];
                FMA4(acc[0][0], a0, w0); FMA4(acc[0][1], a0, w1);
                FMA4(acc[0][2], a0, w2); FMA4(acc[0][3], a0, w3);
                FMA4(acc[1][0], a1, w0); FMA4(acc[1][1], a1, w1);
                FMA4(acc[1][2], a1, w2); FMA4(acc[1][3], a1, w3);
            }

            const int ch = ch0 + chl;
            const float bi = s_bias[chl * 4 + 0], bf = s_bias[chl * 4 + 1];
            const float bg = s_bias[chl * 4 + 2], bo = s_bias[chl * 4 + 3];
            float psum = 0.f, psq = 0.f;
            #pragma unroll
            for (int i = 0; i < 2; ++i) {
                const int b = bb + 128 * i;
                const float ig = fsigmoid(acc[i][0] + bi);
                const float fg = fsigmoid(acc[i][1] + bf);
                const float gg = ftanh   (acc[i][2] + bg);
                const float og = fsigmoid(acc[i][3] + bo);
                const float co = c1[(size_t)b * H1 + ch];
                const float cn = fg * co + ig * gg;
                const float hn = og * ftanh(cn);
                c1[(size_t)b * H1 + ch]  = cn;
                h1c[(size_t)b * H1 + ch] = hn;
                psum += hn; psq += hn * hn;
            }
            #pragma unroll
            for (int off = 32; off > 0; off >>= 1) {
                psum += __shfl_xor(psum, off, 64);
                psq  += __shfl_xor(psq,  off, 64);
            }
            if ((tid & 63) == 0) {
                s_red[(tid >> 6) * 2 + 0] = psum;
                s_red[(tid >> 6) * 2 + 1] = psq;
            }
            __syncthreads();
            if (tid < 4) { // tid == chl
                const int ch2 = ch0 + tid;
                st1[(ch2 * 4 + bgq) * 2 + 0] = s_red[4 * tid + 0] + s_red[4 * tid + 2];
                st1[(ch2 * 4 + bgq) * 2 + 1] = s_red[4 * tid + 1] + s_red[4 * tid + 3];
            }
        }
        grid.sync();

        // ================= Phase 2: BN1 (folded) + L2(t) =================
        if (tid < H1) {
            float s = 0.f, sq = 0.f;
            #pragma unroll
            for (int p = 0; p < 4; ++p) {
                s  += st1[(tid * 4 + p) * 2 + 0];
                sq += st1[(tid * 4 + p) * 2 + 1];
            }
            const float mu  = s * (1.f / B);
            const float var = sq * (1.f / B) - mu * mu;
            const float a   = g1v[tid] * rsqrtf(var + EPS);
            s_a[tid] = a;
            s_d[tid] = b1v[tid] - mu * a;
        }
        for (int idx = tid; idx < 16 * K2; idx += NTHR) {
            const int ch  = idx / (4 * K2);
            const int rem = idx - ch * (4 * K2);
            const int g   = rem / K2;
            const int k   = rem - g * K2;
            const int j   = g * H2 + ch0 + ch;
            s_w[(ch * 4 + g) * K2 + k] = (k < H1) ? Wih2[j * H1 + k] : Whh2[j * H2 + (k - H1)];
        }
        if (tid < 16) {
            const int j = (tid & 3) * H2 + ch0 + (tid >> 2);
            s_bias[tid] = bih2[j] + bhh2[j];
        }
        __syncthreads();

        {
            float acc[2][4];
            #pragma unroll
            for (int i = 0; i < 2; ++i)
                #pragma unroll
                for (int g = 0; g < 4; ++g) acc[i][g] = 0.f;

            const float* wb = &s_w[(chl * 4) * K2];
            const size_t hr0 = (size_t)bb * H1;
            const size_t hr1 = (size_t)(bb + 128) * H1;
            for (int k = 0; k < H1; k += 4) {       // z1 = a*h1c + d on the fly
                const float4 w0 = *(const float4*)&wb[0 * K2 + k];
                const float4 w1 = *(const float4*)&wb[1 * K2 + k];
                const float4 w2 = *(const float4*)&wb[2 * K2 + k];
                const float4 w3 = *(const float4*)&wb[3 * K2 + k];
                const float4 aa = *(const float4*)&s_a[k];
                const float4 dd = *(const float4*)&s_d[k];
                const float4 h0 = *(const float4*)&h1c[hr0 + k];
                const float4 h1v = *(const float4*)&h1c[hr1 + k];
                float4 z0, z1v;
                z0.x = aa.x * h0.x + dd.x;  z0.y = aa.y * h0.y + dd.y;
                z0.z = aa.z * h0.z + dd.z;  z0.w = aa.w * h0.w + dd.w;
                z1v.x = aa.x * h1v.x + dd.x; z1v.y = aa.y * h1v.y + dd.y;
                z1v.z = aa.z * h1v.z + dd.z; z1v.w = aa.w * h1v.w + dd.w;
                FMA4(acc[0][0], z0, w0);  FMA4(acc[0][1], z0, w1);
                FMA4(acc[0][2], z0, w2);  FMA4(acc[0][3], z0, w3);
                FMA4(acc[1][0], z1v, w0); FMA4(acc[1][1], z1v, w1);
                FMA4(acc[1][2], z1v, w2); FMA4(acc[1][3], z1v, w3);
            }
            const size_t gr0 = (size_t)bb * H2;
            const size_t gr1 = (size_t)(bb + 128) * H2;
            for (int k = 0; k < H2; k += 4) {       // h2(t-1) part
                const float4 w0 = *(const float4*)&wb[0 * K2 + H1 + k];
                const float4 w1 = *(const float4*)&wb[1 * K2 + H1 + k];
                const float4 w2 = *(const float4*)&wb[2 * K2 + H1 + k];
                const float4 w3 = *(const float4*)&wb[3 * K2 + H1 + k];
                const float4 a0 = *(const float4*)&h2p[gr0 + k];
                const float4 a1 = *(const float4*)&h2p[gr1 + k];
                FMA4(acc[0][0], a0, w0); FMA4(acc[0][1], a0, w1);
                FMA4(acc[0][2], a0, w2); FMA4(acc[0][3], a0, w3);
                FMA4(acc[1][0], a1, w0); FMA4(acc[1][1], a1, w1);
                FMA4(acc[1][2], a1, w2); FMA4(acc[1][3], a1, w3);
            }

            const int ch = ch0 + chl;
            const float bi = s_bias[chl * 4 + 0], bf = s_bias[chl * 4 + 1];
            const float bg = s_bias[chl * 4 + 2], bo = s_bias[chl * 4 + 3];
            float psum = 0.f, psq = 0.f;
            #pragma unroll
            for (int i = 0; i < 2; ++i) {
                const int b = bb + 128 * i;
                const float ig = fsigmoid(acc[i][0] + bi);
                const float fg = fsigmoid(acc[i][1] + bf);
                const float gg = ftanh   (acc[i][2] + bg);
                const float og = fsigmoid(acc[i][3] + bo);
                const float co = c2[(size_t)b * H2 + ch];
                const float cn = fg * co + ig * gg;
                const float hn = og * ftanh(cn);
                c2[(size_t)b * H2 + ch]  = cn;
                h2c[(size_t)b * H2 + ch] = hn;
                psum += hn; psq += hn * hn;
            }
            #pragma unroll
            for (int off = 32; off > 0; off >>= 1) {
                psum += __shfl_xor(psum, off, 64);
                psq  += __shfl_xor(psq,  off, 64);
            }
            if ((tid & 63) == 0) {
                s_red[(tid >> 6) * 2 + 0] = psum;
                s_red[(tid >> 6) * 2 + 1] = psq;
            }
            __syncthreads();
            if (tid < 4) {
                const int ch2 = ch0 + tid;
                st2[(ch2 * 4 + bgq) * 2 + 0] = s_red[4 * tid + 0] + s_red[4 * tid + 2];
                st2[(ch2 * 4 + bgq) * 2 + 1] = s_red[4 * tid + 1] + s_red[4 * tid + 3];
            }
        }
        grid.sync();

        // ================= Phase 3: BN2 (folded) + L3(t) =================
        if (tid < H2) {
            float s = 0.f, sq = 0.f;
            #pragma unroll
            for (int p = 0; p < 4; ++p) {
                s  += st2[(tid * 4 + p) * 2 + 0];
                sq += st2[(tid * 4 + p) * 2 + 1];
            }
            const float mu  = s * (1.f / B);
            const float var = sq * (1.f / B) - mu * mu;
            const float a   = g2v[tid] * rsqrtf(var + EPS);
            s_a[tid] = a;
            s_d[tid] = b2v[tid] - mu * a;
        }
        const int ch3 = blk >> 3;   // 0..31
        const int bg3 = blk & 7;    // 0..7 (128 b each)
        for (int idx = tid; idx < 4 * K3; idx += NTHR) {
            const int g = idx / K3;
            const int k = idx - g * K3;
            const int j = g * H3 + ch3;
            s_w[g * K3 + k] = (k < H2) ? Wih3[j * H2 + k] : Whh3[j * H3 + (k - H2)];
        }
        if (tid < 4) {
            const int j = tid * H3 + ch3;
            s_bias[tid] = bih3[j] + bhh3[j];
        }
        __syncthreads();

        {
            float psum = 0.f, psq = 0.f;
            if (tid < 128) {
                const int b = bg3 * 128 + tid;
                float a0 = 0.f, a1s = 0.f, a2s = 0.f, a3s = 0.f;
                const size_t gr = (size_t)b * H2;
                for (int k = 0; k < H2; k += 4) {
                    const float4 aa = *(const float4*)&s_a[k];
                    const float4 dd = *(const float4*)&s_d[k];
                    const float4 hv = *(const float4*)&h2c[gr + k];
                    float4 zv;
                    zv.x = aa.x * hv.x + dd.x; zv.y = aa.y * hv.y + dd.y;
                    zv.z = aa.z * hv.z + dd.z; zv.w = aa.w * hv.w + dd.w;
                    const float4 w0 = *(const float4*)&s_w[0 * K3 + k];
                    const float4 w1 = *(const float4*)&s_w[1 * K3 + k];
                    const float4 w2 = *(const float4*)&s_w[2 * K3 + k];
                    const float4 w3 = *(const float4*)&s_w[3 * K3 + k];
                    FMA4(a0, zv, w0); FMA4(a1s, zv, w1);
                    FMA4(a2s, zv, w2); FMA4(a3s, zv, w3);
                }
                const size_t hr = (size_t)b * H3;
                for (int k = 0; k < H3; k += 4) {
                    const float4 hv = *(const float4*)&h3p[hr + k];
                    const float4 w0 = *(const float4*)&s_w[0 * K3 + H2 + k];
                    const float4 w1 = *(const float4*)&s_w[1 * K3 + H2 + k];
                    const float4 w2 = *(const float4*)&s_w[2 * K3 + H2 + k];
                    const float4 w3 = *(const float4*)&s_w[3 * K3 + H2 + k];
                    FMA4(a0, hv, w0); FMA4(a1s, hv, w1);
                    FMA4(a2s, hv, w2); FMA4(a3s, hv, w3);
                }
                const float ig = fsigmoid(a0  + s_bias[0]);
                const float fg = fsigmoid(a1s + s_bias[1]);
                const float gg = ftanh   (a2s + s_bias[2]);
                const float og = fsigmoid(a3s + s_bias[3]);
                const float co = c3[(size_t)b * H3 + ch3];
                const float cn = fg * co + ig * gg;
                const float hn = og * ftanh(cn);
                c3[(size_t)b * H3 + ch3]  = cn;
                h3c[(size_t)b * H3 + ch3] = hn;
                psum = hn; psq = hn * hn;
            }
            #pragma unroll
            for (int off = 32; off > 0; off >>= 1) {
                psum += __shfl_xor(psum, off, 64);
                psq  += __shfl_xor(psq,  off, 64);
            }
            if ((tid & 63) == 0 && tid < 128) {
                s_red[(tid >> 6) * 2 + 0] = psum;
                s_red[(tid >> 6) * 2 + 1] = psq;
            }
            __syncthreads();
            if (tid == 0) {
                st3[(ch3 * 8 + bg3) * 2 + 0] = s_red[0] + s_red[2];
                st3[(ch3 * 8 + bg3) * 2 + 1] = s_red[1] + s_red[3];
            }
        }
        grid.sync();
    }

    // final head for t = T-1 (h3 state lives in buffer (T & 1) == 0)
    if (blk < 4)
        head_pass(blk, tid, T - 1, h3buf + (T & 1) * (B * H3), st3,
                  g3v, b3v, Wl, bl, Wl2, bl2, out, s_a3, s_d3);
}

extern "C" void kernel_launch(void* const* d_in, const int* in_sizes, int n_in,
                              void* d_out, int out_size, void* d_ws, size_t ws_size,
                              hipStream_t stream) {
    const float* x    = (const float*)d_in[0];
    const float* Wih1 = (const float*)d_in[1];
    const float* Whh1 = (const float*)d_in[2];
    const float* bih1 = (const float*)d_in[3];
    const float* bhh1 = (const float*)d_in[4];
    const float* g1   = (const float*)d_in[5];
    const float* b1   = (const float*)d_in[6];
    const float* Wih2 = (const float*)d_in[7];
    const float* Whh2 = (const float*)d_in[8];
    const float* bih2 = (const float*)d_in[9];
    const float* bhh2 = (const float*)d_in[10];
    const float* g2   = (const float*)d_in[11];
    const float* b2   = (const float*)d_in[12];
    const float* Wih3 = (const float*)d_in[13];
    const float* Whh3 = (const float*)d_in[14];
    const float* bih3 = (const float*)d_in[15];
    const float* bhh3 = (const float*)d_in[16];
    const float* g3   = (const float*)d_in[17];
    const float* b3   = (const float*)d_in[18];
    const float* Wl   = (const float*)d_in[19];
    const float* bl   = (const float*)d_in[20];
    const float* Wl2  = (const float*)d_in[21];
    const float* bl2  = (const float*)d_in[22];
    float* out = (float*)d_out;
    float* ws  = (float*)d_ws;

    void* args[] = { &x, &Wih1, &Whh1, &bih1, &bhh1, &g1, &b1,
                     &Wih2, &Whh2, &bih2, &bhh2, &g2, &b2,
                     &Wih3, &Whh3, &bih3, &bhh3, &g3, &b3,
                     &Wl, &bl, &Wl2, &bl2, &out, &ws };
    hipLaunchCooperativeKernel((const void*)cryptonet_kernel, dim3(NBLK), dim3(NTHR),
                               args, 0, stream);
}

// Round 2
// 54420.471 us; speedup vs baseline: 1.1276x; 1.1276x over previous
//
#include <hip/hip_runtime.h>
#include <hip/hip_cooperative_groups.h>

namespace cg = cooperative_groups;

#define B   1024
#define T   256
#define IN  128
#define H1  256
#define H2  256
#define H3  32
#define K1  (IN + H1)   // 384
#define K2  (H1 + H2)   // 512
#define K3  (H2 + H3)   // 288
#define NBLK 256
#define NTHR 512
#define EPS 1e-5f

// ws layout (float offsets) — ALL state arrays are CHANNEL-MAJOR: arr[ch*B + b]
#define WS_XT   0                          // [2][IN*B] x transposed per step
#define WS_H1   (WS_XT + 2 * IN * B)       // [2][H1*B]
#define WS_C1   (WS_H1 + 2 * H1 * B)       // [H1*B]
#define WS_H2   (WS_C1 + H1 * B)           // [2][H2*B]
#define WS_C2   (WS_H2 + 2 * H2 * B)       // [H2*B]
#define WS_H3   (WS_C2 + H2 * B)           // [2][H3*B]
#define WS_C3   (WS_H3 + 2 * H3 * B)       // [H3*B]
#define WS_S1   (WS_C3 + H3 * B)           // [H1][4][2] partial (sum,sumsq)
#define WS_S2   (WS_S1 + H1 * 4 * 2)       // [H2][4][2]
#define WS_S3   (WS_S2 + H2 * 4 * 2)       // [H3][8][2]

__device__ __forceinline__ float fsigmoid(float v) { return 1.f / (1.f + __expf(-v)); }
__device__ __forceinline__ float ftanh(float v)    { return 1.f - 2.f / (__expf(2.f * v) + 1.f); }

__device__ __forceinline__ float lstm_point(float gi, float gf, float gg, float go, float& c) {
    const float i = fsigmoid(gi), f = fsigmoid(gf), g = ftanh(gg), o = fsigmoid(go);
    c = f * c + i * g;
    return o * ftanh(c);
}

// 4 gate weight rows (float4 over k..k+3), LDS broadcast
#define LOAD_W4(WB, KS, OFF) \
    const float4 w0 = *(const float4*)&(WB)[0 * (KS) + (OFF)]; \
    const float4 w1 = *(const float4*)&(WB)[1 * (KS) + (OFF)]; \
    const float4 w2 = *(const float4*)&(WB)[2 * (KS) + (OFF)]; \
    const float4 w3 = *(const float4*)&(WB)[3 * (KS) + (OFF)];

// activations for rows (bpos, bpos+1) at k..k+3, coalesced dwordx2
#define LOAD_A4(SRC, KK) \
    const float2 aA = *(const float2*)&(SRC)[(size_t)((KK) + 0) * B + bpos]; \
    const float2 aB = *(const float2*)&(SRC)[(size_t)((KK) + 1) * B + bpos]; \
    const float2 aC = *(const float2*)&(SRC)[(size_t)((KK) + 2) * B + bpos]; \
    const float2 aD = *(const float2*)&(SRC)[(size_t)((KK) + 3) * B + bpos];

// same, but apply folded BN z = a*h + d on the fly
#define LOAD_Z4(SRC, KK) \
    const float4 av = *(const float4*)&s_a[(KK)]; \
    const float4 dv = *(const float4*)&s_d[(KK)]; \
    float2 aA, aB, aC, aD; \
    { const float2 h_ = *(const float2*)&(SRC)[(size_t)((KK) + 0) * B + bpos]; aA.x = av.x*h_.x + dv.x; aA.y = av.x*h_.y + dv.x; } \
    { const float2 h_ = *(const float2*)&(SRC)[(size_t)((KK) + 1) * B + bpos]; aB.x = av.y*h_.x + dv.y; aB.y = av.y*h_.y + dv.y; } \
    { const float2 h_ = *(const float2*)&(SRC)[(size_t)((KK) + 2) * B + bpos]; aC.x = av.z*h_.x + dv.z; aC.y = av.z*h_.y + dv.z; } \
    { const float2 h_ = *(const float2*)&(SRC)[(size_t)((KK) + 3) * B + bpos]; aD.x = av.w*h_.x + dv.w; aD.y = av.w*h_.y + dv.w; }

#define ACC_ROWS() \
    ar0[0] += aA.x*w0.x + aB.x*w0.y + aC.x*w0.z + aD.x*w0.w; \
    ar1[0] += aA.y*w0.x + aB.y*w0.y + aC.y*w0.z + aD.y*w0.w; \
    ar0[1] += aA.x*w1.x + aB.x*w1.y + aC.x*w1.z + aD.x*w1.w; \
    ar1[1] += aA.y*w1.x + aB.y*w1.y + aC.y*w1.z + aD.y*w1.w; \
    ar0[2] += aA.x*w2.x + aB.x*w2.y + aC.x*w2.z + aD.x*w2.w; \
    ar1[2] += aA.y*w2.x + aB.y*w2.y + aC.y*w2.z + aD.y*w2.w; \
    ar0[3] += aA.x*w3.x + aB.x*w3.y + aC.x*w3.z + aD.x*w3.w; \
    ar1[3] += aA.y*w3.x + aB.y*w3.y + aC.y*w3.z + aD.y*w3.w;

__global__ void __launch_bounds__(NTHR, 1) cryptonet_kernel(
    const float* __restrict__ x,
    const float* __restrict__ Wih1, const float* __restrict__ Whh1,
    const float* __restrict__ bih1, const float* __restrict__ bhh1,
    const float* __restrict__ g1v,  const float* __restrict__ b1v,
    const float* __restrict__ Wih2, const float* __restrict__ Whh2,
    const float* __restrict__ bih2, const float* __restrict__ bhh2,
    const float* __restrict__ g2v,  const float* __restrict__ b2v,
    const float* __restrict__ Wih3, const float* __restrict__ Whh3,
    const float* __restrict__ bih3, const float* __restrict__ bhh3,
    const float* __restrict__ g3v,  const float* __restrict__ b3v,
    const float* __restrict__ Wl,   const float* __restrict__ bl,
    const float* __restrict__ Wl2,  const float* __restrict__ bl2,
    float* __restrict__ out, float* __restrict__ ws)
{
    cg::grid_group grid = cg::this_grid();
    const int tid = threadIdx.x;
    const int blk = blockIdx.x;

    // persistent weight staging (once) — total static LDS 64,464 B <= 64 KB
    __shared__ __align__(16) float s_w1[16 * K1];   // 24576 B
    __shared__ __align__(16) float s_w2[16 * K2];   // 32768 B
    __shared__ __align__(16) float s_w3[4 * K3];    //  4608 B
    __shared__ __align__(16) float s_a[H1], s_d[H1];
    __shared__ __align__(16) float s_a3[H3], s_d3[H3];
    __shared__ float s_b1[16], s_b2[16], s_b3[4];
    __shared__ float s_red[16];

    float* xT    = ws + WS_XT;
    float* h1buf = ws + WS_H1;
    float* c1    = ws + WS_C1;
    float* h2buf = ws + WS_H2;
    float* c2    = ws + WS_C2;
    float* h3buf = ws + WS_H3;
    float* c3    = ws + WS_C3;
    float* st1   = ws + WS_S1;
    float* st2   = ws + WS_S2;
    float* st3   = ws + WS_S3;

    const int cgq = blk >> 2;          // 64 channel-groups (4 ch) for L1/L2
    const int bgq = blk & 3;           // 4 batch-groups (256 b)
    const int ch0 = cgq * 4;
    const int chl = tid >> 7;          // 0..3
    const int bt  = tid & 127;
    const int bpos = bgq * 256 + 2 * bt;   // rows bpos, bpos+1 (adjacent!)
    const int wv  = tid >> 6;          // wave index 0..7
    const int ch3 = blk >> 3;          // L3: 32 ch x 8 batch-groups
    const int bg3 = blk & 7;

    // ---------- stage all weights into LDS once ----------
    for (int idx = tid; idx < 16 * K1; idx += NTHR) {
        const int ch = idx / (4 * K1); const int rem = idx - ch * (4 * K1);
        const int g = rem / K1;        const int k = rem - g * K1;
        const int j = g * H1 + ch0 + ch;
        s_w1[(ch * 4 + g) * K1 + k] = (k < IN) ? Wih1[j * IN + k] : Whh1[j * H1 + (k - IN)];
    }
    for (int idx = tid; idx < 16 * K2; idx += NTHR) {
        const int ch = idx / (4 * K2); const int rem = idx - ch * (4 * K2);
        const int g = rem / K2;        const int k = rem - g * K2;
        const int j = g * H2 + ch0 + ch;
        s_w2[(ch * 4 + g) * K2 + k] = (k < H1) ? Wih2[j * H1 + k] : Whh2[j * H2 + (k - H1)];
    }
    for (int idx = tid; idx < 4 * K3; idx += NTHR) {
        const int g = idx / K3; const int k = idx - g * K3;
        const int j = g * H3 + ch3;
        s_w3[g * K3 + k] = (k < H2) ? Wih3[j * H2 + k] : Whh3[j * H3 + (k - H2)];
    }
    if (tid < 16) { const int j = (tid & 3) * H1 + ch0 + (tid >> 2); s_b1[tid] = bih1[j] + bhh1[j]; }
    else if (tid < 32) { const int t2 = tid - 16; const int j = (t2 & 3) * H2 + ch0 + (t2 >> 2); s_b2[t2] = bih2[j] + bhh2[j]; }
    else if (tid < 36) { const int t3 = tid - 32; const int j = t3 * H3 + ch3; s_b3[t3] = bih3[j] + bhh3[j]; }

    // ---------- zero state, stage xT for t=0 ----------
    {
        const int gt = blk * NTHR + tid, gs = NBLK * NTHR;
        for (int i = gt; i < 2 * H1 * B; i += gs) h1buf[i] = 0.f;
        for (int i = gt; i < H1 * B; i += gs) c1[i] = 0.f;
        for (int i = gt; i < 2 * H2 * B; i += gs) h2buf[i] = 0.f;
        for (int i = gt; i < H2 * B; i += gs) c2[i] = 0.f;
        for (int i = gt; i < 2 * H3 * B; i += gs) h3buf[i] = 0.f;
        for (int i = gt; i < H3 * B; i += gs) c3[i] = 0.f;
        // xT[0][k][b] = x[b][0][k] — one element per thread (coalesced read over k)
        const int b = blk * 4 + (tid >> 7), k = tid & 127;
        xT[(size_t)k * B + b] = x[(size_t)b * T * IN + k];
    }
    grid.sync();

    for (int t = 0; t < T; ++t) {
        const float* xTc = xT + (t & 1) * (IN * B);
        const float* h1p = h1buf + (t & 1) * (H1 * B);
        float*       h1c = h1buf + ((t + 1) & 1) * (H1 * B);
        const float* h2p = h2buf + (t & 1) * (H2 * B);
        float*       h2c = h2buf + ((t + 1) & 1) * (H2 * B);
        const float* h3p = h3buf + (t & 1) * (H3 * B);
        float*       h3c = h3buf + ((t + 1) & 1) * (H3 * B);

        // ================= Phase 1: head(t-1) + L1(t) =================
        if (blk < 4 && t > 0) {
            // BN3 + head + softmax for t-1 (blocks 0..3 only)
            if (tid < H3) {
                float s = 0.f, sq = 0.f;
                #pragma unroll
                for (int p = 0; p < 4; ++p) {
                    const float4 q = *(const float4*)&st3[tid * 16 + p * 4];
                    s += q.x + q.z; sq += q.y + q.w;
                }
                const float mu  = s * (1.f / B);
                const float var = sq * (1.f / B) - mu * mu;
                const float a   = g3v[tid] * rsqrtf(var + EPS);
                s_a3[tid] = a; s_d3[tid] = b3v[tid] - mu * a;
            }
            __syncthreads();
            if (tid < 256) {
                const int b = blk * 256 + tid;
                float y0 = bl[0], y1 = bl[1];
                #pragma unroll
                for (int ch = 0; ch < H3; ++ch) {
                    const float z = s_a3[ch] * h3p[(size_t)ch * B + b] + s_d3[ch];
                    y0 += Wl[ch] * z; y1 += Wl[H3 + ch] * z;
                }
                y0 = fmaxf(y0, 0.f); y1 = fmaxf(y1, 0.f);
                const float u0 = Wl2[0] * y0 + Wl2[1] * y1 + bl2[0];
                const float u1 = Wl2[2] * y0 + Wl2[3] * y1 + bl2[1];
                const float m  = fmaxf(u0, u1);
                const float e0 = __expf(u0 - m), e1 = __expf(u1 - m);
                const float inv = 1.f / (e0 + e1);
                out[((size_t)b * T + (t - 1)) * 2 + 0] = e0 * inv;
                out[((size_t)b * T + (t - 1)) * 2 + 1] = e1 * inv;
            }
        }

        {
            float ar0[4] = {0.f, 0.f, 0.f, 0.f};
            float ar1[4] = {0.f, 0.f, 0.f, 0.f};
            const float* wb = &s_w1[(chl * 4) * K1];
            #pragma unroll 2
            for (int k = 0; k < IN; k += 4) {
                LOAD_W4(wb, K1, k)
                LOAD_A4(xTc, k)
                ACC_ROWS()
            }
            #pragma unroll 2
            for (int k = 0; k < H1; k += 4) {
                LOAD_W4(wb, K1, IN + k)
                LOAD_A4(h1p, k)
                ACC_ROWS()
            }
            const int ch = ch0 + chl;
            float2 cc = *(float2*)&c1[(size_t)ch * B + bpos];
            const float b0 = s_b1[chl * 4 + 0], b1 = s_b1[chl * 4 + 1];
            const float b2 = s_b1[chl * 4 + 2], b3 = s_b1[chl * 4 + 3];
            const float hn0 = lstm_point(ar0[0] + b0, ar0[1] + b1, ar0[2] + b2, ar0[3] + b3, cc.x);
            const float hn1 = lstm_point(ar1[0] + b0, ar1[1] + b1, ar1[2] + b2, ar1[3] + b3, cc.y);
            *(float2*)&c1[(size_t)ch * B + bpos]  = cc;
            *(float2*)&h1c[(size_t)ch * B + bpos] = make_float2(hn0, hn1);
            float psum = hn0 + hn1, psq = hn0 * hn0 + hn1 * hn1;
            #pragma unroll
            for (int off = 32; off > 0; off >>= 1) {
                psum += __shfl_xor(psum, off, 64);
                psq  += __shfl_xor(psq,  off, 64);
            }
            if ((tid & 63) == 0) { s_red[wv * 2 + 0] = psum; s_red[wv * 2 + 1] = psq; }
        }
        __syncthreads();
        if (tid < 4) {
            st1[((ch0 + tid) * 4 + bgq) * 2 + 0] = s_red[(2 * tid) * 2 + 0] + s_red[(2 * tid + 1) * 2 + 0];
            st1[((ch0 + tid) * 4 + bgq) * 2 + 1] = s_red[(2 * tid) * 2 + 1] + s_red[(2 * tid + 1) * 2 + 1];
        }
        grid.sync();

        // ================= Phase 2: BN1 (folded) + L2(t) =================
        if (tid < H1) {
            const float4 p0 = *(const float4*)&st1[tid * 8];
            const float4 p1 = *(const float4*)&st1[tid * 8 + 4];
            const float s  = p0.x + p0.z + p1.x + p1.z;
            const float sq = p0.y + p0.w + p1.y + p1.w;
            const float mu  = s * (1.f / B);
            const float var = sq * (1.f / B) - mu * mu;
            const float a   = g1v[tid] * rsqrtf(var + EPS);
            s_a[tid] = a; s_d[tid] = b1v[tid] - mu * a;
        }
        __syncthreads();
        {
            float ar0[4] = {0.f, 0.f, 0.f, 0.f};
            float ar1[4] = {0.f, 0.f, 0.f, 0.f};
            const float* wb = &s_w2[(chl * 4) * K2];
            #pragma unroll 2
            for (int k = 0; k < H1; k += 4) {
                LOAD_W4(wb, K2, k)
                LOAD_Z4(h1c, k)
                ACC_ROWS()
            }
            #pragma unroll 2
            for (int k = 0; k < H2; k += 4) {
                LOAD_W4(wb, K2, H1 + k)
                LOAD_A4(h2p, k)
                ACC_ROWS()
            }
            const int ch = ch0 + chl;
            float2 cc = *(float2*)&c2[(size_t)ch * B + bpos];
            const float b0 = s_b2[chl * 4 + 0], b1 = s_b2[chl * 4 + 1];
            const float b2_ = s_b2[chl * 4 + 2], b3 = s_b2[chl * 4 + 3];
            const float hn0 = lstm_point(ar0[0] + b0, ar0[1] + b1, ar0[2] + b2_, ar0[3] + b3, cc.x);
            const float hn1 = lstm_point(ar1[0] + b0, ar1[1] + b1, ar1[2] + b2_, ar1[3] + b3, cc.y);
            *(float2*)&c2[(size_t)ch * B + bpos]  = cc;
            *(float2*)&h2c[(size_t)ch * B + bpos] = make_float2(hn0, hn1);
            float psum = hn0 + hn1, psq = hn0 * hn0 + hn1 * hn1;
            #pragma unroll
            for (int off = 32; off > 0; off >>= 1) {
                psum += __shfl_xor(psum, off, 64);
                psq  += __shfl_xor(psq,  off, 64);
            }
            if ((tid & 63) == 0) { s_red[wv * 2 + 0] = psum; s_red[wv * 2 + 1] = psq; }
        }
        __syncthreads();
        if (tid < 4) {
            st2[((ch0 + tid) * 4 + bgq) * 2 + 0] = s_red[(2 * tid) * 2 + 0] + s_red[(2 * tid + 1) * 2 + 0];
            st2[((ch0 + tid) * 4 + bgq) * 2 + 1] = s_red[(2 * tid) * 2 + 1] + s_red[(2 * tid + 1) * 2 + 1];
        }
        grid.sync();

        // ================= Phase 3: BN2 (folded) + L3(t) + xT staging =================
        if (tid < H2) {
            const float4 p0 = *(const float4*)&st2[tid * 8];
            const float4 p1 = *(const float4*)&st2[tid * 8 + 4];
            const float s  = p0.x + p0.z + p1.x + p1.z;
            const float sq = p0.y + p0.w + p1.y + p1.w;
            const float mu  = s * (1.f / B);
            const float var = sq * (1.f / B) - mu * mu;
            const float a   = g2v[tid] * rsqrtf(var + EPS);
            s_a[tid] = a; s_d[tid] = b2v[tid] - mu * a;
        }
        __syncthreads();
        if (tid < 128) {
            const int b = bg3 * 128 + tid;
            float a0 = 0.f, a1 = 0.f, a2 = 0.f, a3 = 0.f;
            #pragma unroll 2
            for (int k = 0; k < H2; k += 4) {
                const float4 w0 = *(const float4*)&s_w3[0 * K3 + k];
                const float4 w1 = *(const float4*)&s_w3[1 * K3 + k];
                const float4 w2 = *(const float4*)&s_w3[2 * K3 + k];
                const float4 w3 = *(const float4*)&s_w3[3 * K3 + k];
                const float4 av = *(const float4*)&s_a[k];
                const float4 dv = *(const float4*)&s_d[k];
                const float z0 = av.x * h2c[(size_t)(k + 0) * B + b] + dv.x;
                const float z1 = av.y * h2c[(size_t)(k + 1) * B + b] + dv.y;
                const float z2 = av.z * h2c[(size_t)(k + 2) * B + b] + dv.z;
                const float z3 = av.w * h2c[(size_t)(k + 3) * B + b] + dv.w;
                a0 += z0 * w0.x + z1 * w0.y + z2 * w0.z + z3 * w0.w;
                a1 += z0 * w1.x + z1 * w1.y + z2 * w1.z + z3 * w1.w;
                a2 += z0 * w2.x + z1 * w2.y + z2 * w2.z + z3 * w2.w;
                a3 += z0 * w3.x + z1 * w3.y + z2 * w3.z + z3 * w3.w;
            }
            #pragma unroll 2
            for (int k = 0; k < H3; k += 4) {
                const float4 w0 = *(const float4*)&s_w3[0 * K3 + H2 + k];
                const float4 w1 = *(const float4*)&s_w3[1 * K3 + H2 + k];
                const float4 w2 = *(const float4*)&s_w3[2 * K3 + H2 + k];
                const float4 w3 = *(const float4*)&s_w3[3 * K3 + H2 + k];
                const float z0 = h3p[(size_t)(k + 0) * B + b];
                const float z1 = h3p[(size_t)(k + 1) * B + b];
                const float z2 = h3p[(size_t)(k + 2) * B + b];
                const float z3 = h3p[(size_t)(k + 3) * B + b];
                a0 += z0 * w0.x + z1 * w0.y + z2 * w0.z + z3 * w0.w;
                a1 += z0 * w1.x + z1 * w1.y + z2 * w1.z + z3 * w1.w;
                a2 += z0 * w2.x + z1 * w2.y + z2 * w2.z + z3 * w2.w;
                a3 += z0 * w3.x + z1 * w3.y + z2 * w3.z + z3 * w3.w;
            }
            float cc = c3[(size_t)ch3 * B + b];
            const float hn = lstm_point(a0 + s_b3[0], a1 + s_b3[1], a2 + s_b3[2], a3 + s_b3[3], cc);
            c3[(size_t)ch3 * B + b]  = cc;
            h3c[(size_t)ch3 * B + b] = hn;
            float psum = hn, psq = hn * hn;
            #pragma unroll
            for (int off = 32; off > 0; off >>= 1) {
                psum += __shfl_xor(psum, off, 64);
                psq  += __shfl_xor(psq,  off, 64);
            }
            if ((tid & 63) == 0) { s_red[(tid >> 6) * 2 + 0] = psum; s_red[(tid >> 6) * 2 + 1] = psq; }
        } else if (tid >= 256 && t + 1 < T) {
            // stage xT for step t+1: coalesced x reads, scattered (L2-combined) writes
            const int tt = tid - 256;
            const int b  = blk * 4 + (tt >> 6);
            const int kk = (tt & 63) * 2;
            const float2 v = *(const float2*)&x[((size_t)b * T + (t + 1)) * IN + kk];
            float* xTn = xT + ((t + 1) & 1) * (IN * B);
            xTn[(size_t)kk * B + b]       = v.x;
            xTn[(size_t)(kk + 1) * B + b] = v.y;
        }
        __syncthreads();
        if (tid == 0) {
            st3[(ch3 * 8 + bg3) * 2 + 0] = s_red[0] + s_red[2];
            st3[(ch3 * 8 + bg3) * 2 + 1] = s_red[1] + s_red[3];
        }
        grid.sync();
    }

    // final head for t = T-1
    if (blk < 4) {
        const float* h3s = h3buf + (T & 1) * (H3 * B);
        if (tid < H3) {
            float s = 0.f, sq = 0.f;
            #pragma unroll
            for (int p = 0; p < 4; ++p) {
                const float4 q = *(const float4*)&st3[tid * 16 + p * 4];
                s += q.x + q.z; sq += q.y + q.w;
            }
            const float mu  = s * (1.f / B);
            const float var = sq * (1.f / B) - mu * mu;
            const float a   = g3v[tid] * rsqrtf(var + EPS);
            s_a3[tid] = a; s_d3[tid] = b3v[tid] - mu * a;
        }
        __syncthreads();
        if (tid < 256) {
            const int b = blk * 256 + tid;
            float y0 = bl[0], y1 = bl[1];
            #pragma unroll
            for (int ch = 0; ch < H3; ++ch) {
                const float z = s_a3[ch] * h3s[(size_t)ch * B + b] + s_d3[ch];
                y0 += Wl[ch] * z; y1 += Wl[H3 + ch] * z;
            }
            y0 = fmaxf(y0, 0.f); y1 = fmaxf(y1, 0.f);
            const float u0 = Wl2[0] * y0 + Wl2[1] * y1 + bl2[0];
            const float u1 = Wl2[2] * y0 + Wl2[3] * y1 + bl2[1];
            const float m  = fmaxf(u0, u1);
            const float e0 = __expf(u0 - m), e1 = __expf(u1 - m);
            const float inv = 1.f / (e0 + e1);
            out[((size_t)b * T + (T - 1)) * 2 + 0] = e0 * inv;
            out[((size_t)b * T + (T - 1)) * 2 + 1] = e1 * inv;
        }
    }
}

extern "C" void kernel_launch(void* const* d_in, const int* in_sizes, int n_in,
                              void* d_out, int out_size, void* d_ws, size_t ws_size,
                              hipStream_t stream) {
    const float* x    = (const float*)d_in[0];
    const float* Wih1 = (const float*)d_in[1];
    const float* Whh1 = (const float*)d_in[2];
    const float* bih1 = (const float*)d_in[3];
    const float* bhh1 = (const float*)d_in[4];
    const float* g1   = (const float*)d_in[5];
    const float* b1   = (const float*)d_in[6];
    const float* Wih2 = (const float*)d_in[7];
    const float* Whh2 = (const float*)d_in[8];
    const float* bih2 = (const float*)d_in[9];
    const float* bhh2 = (const float*)d_in[10];
    const float* g2   = (const float*)d_in[11];
    const float* b2   = (const float*)d_in[12];
    const float* Wih3 = (const float*)d_in[13];
    const float* Whh3 = (const float*)d_in[14];
    const float* bih3 = (const float*)d_in[15];
    const float* bhh3 = (const float*)d_in[16];
    const float* g3   = (const float*)d_in[17];
    const float* b3   = (const float*)d_in[18];
    const float* Wl   = (const float*)d_in[19];
    const float* bl   = (const float*)d_in[20];
    const float* Wl2  = (const float*)d_in[21];
    const float* bl2  = (const float*)d_in[22];
    float* out = (float*)d_out;
    float* ws  = (float*)d_ws;

    void* args[] = { &x, &Wih1, &Whh1, &bih1, &bhh1, &g1, &b1,
                     &Wih2, &Whh2, &bih2, &bhh2, &g2, &b2,
                     &Wih3, &Whh3, &bih3, &bhh3, &g3, &b3,
                     &Wl, &bl, &Wl2, &bl2, &out, &ws };
    hipLaunchCooperativeKernel((const void*)cryptonet_kernel, dim3(NBLK), dim3(NTHR),
                               args, 0, stream);
}

// Round 3
// 40146.481 us; speedup vs baseline: 1.5285x; 1.3555x over previous
//
#include <hip/hip_runtime.h>
#include <hip/hip_cooperative_groups.h>

namespace cg = cooperative_groups;

#define B   1024
#define T   256
#define IN  128
#define H1  256
#define H2  256
#define H3  32
#define K1  (IN + H1)   // 384
#define K2  (H1 + H2)   // 512
#define K3  (H2 + H3)   // 288
#define NBLK 256
#define NTHR 512
#define TK   32
#define EPS 1e-5f

// ws layout (float offsets) — ALL state arrays are CHANNEL-MAJOR: arr[ch*B + b]
#define WS_XT   0                          // [2][IN*B] x transposed per step
#define WS_H1   (WS_XT + 2 * IN * B)       // [2][H1*B]
#define WS_C1   (WS_H1 + 2 * H1 * B)       // [H1*B]
#define WS_H2   (WS_C1 + H1 * B)           // [2][H2*B]
#define WS_C2   (WS_H2 + 2 * H2 * B)       // [H2*B]
#define WS_H3   (WS_C2 + H2 * B)           // [2][H3*B]
#define WS_C3   (WS_H3 + 2 * H3 * B)       // [H3*B]
#define WS_S1   (WS_C3 + H3 * B)           // [H1][4][2] partial (sum,sumsq)
#define WS_S2   (WS_S1 + H1 * 4 * 2)       // [H2][4][2]
#define WS_S3   (WS_S2 + H2 * 4 * 2)       // [H3][8][2]

__device__ __forceinline__ float fsigmoid(float v) { return 1.f / (1.f + __expf(-v)); }
__device__ __forceinline__ float ftanh(float v)    { return 1.f - 2.f / (__expf(2.f * v) + 1.f); }

__device__ __forceinline__ float lstm_point(float gi, float gf, float gg, float go, float& c) {
    const float i = fsigmoid(gi), f = fsigmoid(gf), g = ftanh(gg), o = fsigmoid(go);
    c = f * c + i * g;
    return o * ftanh(c);
}

// async global->LDS, 16B per lane; LDS dest = wave-uniform base + lane*16
__device__ __forceinline__ void gld16(const float* g, float* l) {
    __builtin_amdgcn_global_load_lds(
        (const __attribute__((address_space(1))) unsigned int*)g,
        (__attribute__((address_space(3))) unsigned int*)l, 16, 0, 0);
}

#define ACC_ROWS() \
    ar0[0] += aA.x*w0.x + aB.x*w0.y + aC.x*w0.z + aD.x*w0.w; \
    ar1[0] += aA.y*w0.x + aB.y*w0.y + aC.y*w0.z + aD.y*w0.w; \
    ar0[1] += aA.x*w1.x + aB.x*w1.y + aC.x*w1.z + aD.x*w1.w; \
    ar1[1] += aA.y*w1.x + aB.y*w1.y + aC.y*w1.z + aD.y*w1.w; \
    ar0[2] += aA.x*w2.x + aB.x*w2.y + aC.x*w2.z + aD.x*w2.w; \
    ar1[2] += aA.y*w2.x + aB.y*w2.y + aC.y*w2.z + aD.y*w2.w; \
    ar0[3] += aA.x*w3.x + aB.x*w3.y + aC.x*w3.z + aD.x*w3.w; \
    ar1[3] += aA.y*w3.x + aB.y*w3.y + aC.y*w3.z + aD.y*w3.w;

// compute one 32-k tile: weights from LDS (broadcast b128), acts from LDS tile (b64)
#define P12_TILE(WB, KS, K0, SACT) \
    _Pragma("unroll") \
    for (int kk = 0; kk < TK; kk += 4) { \
        const float4 w0 = *(const float4*)&(WB)[0*(KS) + (K0) + kk]; \
        const float4 w1 = *(const float4*)&(WB)[1*(KS) + (K0) + kk]; \
        const float4 w2 = *(const float4*)&(WB)[2*(KS) + (K0) + kk]; \
        const float4 w3 = *(const float4*)&(WB)[3*(KS) + (K0) + kk]; \
        const float2 aA = *(const float2*)&(SACT)[(kk+0)*256 + bpos2]; \
        const float2 aB = *(const float2*)&(SACT)[(kk+1)*256 + bpos2]; \
        const float2 aC = *(const float2*)&(SACT)[(kk+2)*256 + bpos2]; \
        const float2 aD = *(const float2*)&(SACT)[(kk+3)*256 + bpos2]; \
        ACC_ROWS() \
    }

// same with folded BN applied to the staged activations
#define P2F_TILE(WB, KS, K0, SACT) \
    _Pragma("unroll") \
    for (int kk = 0; kk < TK; kk += 4) { \
        const float4 w0 = *(const float4*)&(WB)[0*(KS) + (K0) + kk]; \
        const float4 w1 = *(const float4*)&(WB)[1*(KS) + (K0) + kk]; \
        const float4 w2 = *(const float4*)&(WB)[2*(KS) + (K0) + kk]; \
        const float4 w3 = *(const float4*)&(WB)[3*(KS) + (K0) + kk]; \
        const float4 av = *(const float4*)&s_a[(K0) + kk]; \
        const float4 dv = *(const float4*)&s_d[(K0) + kk]; \
        float2 aA = *(const float2*)&(SACT)[(kk+0)*256 + bpos2]; \
        float2 aB = *(const float2*)&(SACT)[(kk+1)*256 + bpos2]; \
        float2 aC = *(const float2*)&(SACT)[(kk+2)*256 + bpos2]; \
        float2 aD = *(const float2*)&(SACT)[(kk+3)*256 + bpos2]; \
        aA.x = av.x*aA.x + dv.x; aA.y = av.x*aA.y + dv.x; \
        aB.x = av.y*aB.x + dv.y; aB.y = av.y*aB.y + dv.y; \
        aC.x = av.z*aC.x + dv.z; aC.y = av.z*aC.y + dv.z; \
        aD.x = av.w*aD.x + dv.w; aD.y = av.w*aD.y + dv.w; \
        ACC_ROWS() \
    }

__global__ void __launch_bounds__(NTHR, 1) cryptonet_kernel(
    const float* __restrict__ x,
    const float* __restrict__ Wih1, const float* __restrict__ Whh1,
    const float* __restrict__ bih1, const float* __restrict__ bhh1,
    const float* __restrict__ g1v,  const float* __restrict__ b1v,
    const float* __restrict__ Wih2, const float* __restrict__ Whh2,
    const float* __restrict__ bih2, const float* __restrict__ bhh2,
    const float* __restrict__ g2v,  const float* __restrict__ b2v,
    const float* __restrict__ Wih3, const float* __restrict__ Whh3,
    const float* __restrict__ bih3, const float* __restrict__ bhh3,
    const float* __restrict__ g3v,  const float* __restrict__ b3v,
    const float* __restrict__ Wl,   const float* __restrict__ bl,
    const float* __restrict__ Wl2,  const float* __restrict__ bl2,
    float* __restrict__ out, float* __restrict__ ws)
{
    cg::grid_group grid = cg::this_grid();
    const int tid = threadIdx.x;
    const int blk = blockIdx.x;

    // static LDS: 64,464 B (persistent weights) + dynamic 64 KB act tiles
    __shared__ __align__(16) float s_w1[16 * K1];   // 24576 B
    __shared__ __align__(16) float s_w2[16 * K2];   // 32768 B
    __shared__ __align__(16) float s_w3[4 * K3];    //  4608 B
    __shared__ __align__(16) float s_a[H1], s_d[H1];
    __shared__ __align__(16) float s_a3[H3], s_d3[H3];
    __shared__ float s_b1[16], s_b2[16], s_b3[4];
    __shared__ float s_red[16];
    extern __shared__ float s_act_dyn[];            // [2][TK*256] = 65536 B
    float* sact0 = s_act_dyn;
    float* sact1 = s_act_dyn + TK * 256;

    float* xT    = ws + WS_XT;
    float* h1buf = ws + WS_H1;
    float* c1    = ws + WS_C1;
    float* h2buf = ws + WS_H2;
    float* c2    = ws + WS_C2;
    float* h3buf = ws + WS_H3;
    float* c3    = ws + WS_C3;
    float* st1   = ws + WS_S1;
    float* st2   = ws + WS_S2;
    float* st3   = ws + WS_S3;

    const int cgq = blk >> 2;              // 64 channel-groups (4 ch) for L1/L2
    const int bgq = blk & 3;               // 4 batch-groups (256 b)
    const int ch0 = cgq * 4;
    const int chl = tid >> 7;              // 0..3
    const int bt  = tid & 127;
    const int bpos2 = 2 * bt;              // row offset within 256-row slice
    const int bposA = bgq * 256 + bpos2;   // absolute rows bposA, bposA+1
    const int wv  = tid >> 6;              // wave 0..7
    const int lane = tid & 63;
    const int ch3 = blk >> 3;              // L3: 32 ch x 8 batch-groups of 128
    const int bg3 = blk & 7;

    // stage a 32-row x 256-float slice (row stride B) into LDS tile
    auto stage256 = [&](const float* src, float* dst) {
        #pragma unroll
        for (int r = 0; r < 4; ++r) {
            const int k = wv * 4 + r;
            gld16(src + (size_t)k * B + lane * 4, dst + k * 256);
        }
    };
    // stage a 32-row x 128-float slice: 2 rows per instruction
    auto stage128 = [&](const float* src, float* dst) {
        #pragma unroll
        for (int j = 0; j < 2; ++j) {
            const int m = wv * 2 + j;
            gld16(src + (size_t)(2 * m + (lane >> 5)) * B + (lane & 31) * 4,
                  dst + m * 256);
        }
    };

    // ---------- stage all weights into LDS once ----------
    for (int idx = tid; idx < 16 * K1; idx += NTHR) {
        const int ch = idx / (4 * K1); const int rem = idx - ch * (4 * K1);
        const int g = rem / K1;        const int k = rem - g * K1;
        const int j = g * H1 + ch0 + ch;
        s_w1[(ch * 4 + g) * K1 + k] = (k < IN) ? Wih1[j * IN + k] : Whh1[j * H1 + (k - IN)];
    }
    for (int idx = tid; idx < 16 * K2; idx += NTHR) {
        const int ch = idx / (4 * K2); const int rem = idx - ch * (4 * K2);
        const int g = rem / K2;        const int k = rem - g * K2;
        const int j = g * H2 + ch0 + ch;
        s_w2[(ch * 4 + g) * K2 + k] = (k < H1) ? Wih2[j * H1 + k] : Whh2[j * H2 + (k - H1)];
    }
    for (int idx = tid; idx < 4 * K3; idx += NTHR) {
        const int g = idx / K3; const int k = idx - g * K3;
        const int j = g * H3 + ch3;
        s_w3[g * K3 + k] = (k < H2) ? Wih3[j * H2 + k] : Whh3[j * H3 + (k - H2)];
    }
    if (tid < 16) { const int j = (tid & 3) * H1 + ch0 + (tid >> 2); s_b1[tid] = bih1[j] + bhh1[j]; }
    else if (tid < 32) { const int t2 = tid - 16; const int j = (t2 & 3) * H2 + ch0 + (t2 >> 2); s_b2[t2] = bih2[j] + bhh2[j]; }
    else if (tid < 36) { const int t3 = tid - 32; const int j = t3 * H3 + ch3; s_b3[t3] = bih3[j] + bhh3[j]; }

    // ---------- zero state, stage xT for t=0 ----------
    {
        const int gt = blk * NTHR + tid, gs = NBLK * NTHR;
        for (int i = gt; i < 2 * H1 * B; i += gs) h1buf[i] = 0.f;
        for (int i = gt; i < H1 * B; i += gs) c1[i] = 0.f;
        for (int i = gt; i < 2 * H2 * B; i += gs) h2buf[i] = 0.f;
        for (int i = gt; i < H2 * B; i += gs) c2[i] = 0.f;
        for (int i = gt; i < 2 * H3 * B; i += gs) h3buf[i] = 0.f;
        for (int i = gt; i < H3 * B; i += gs) c3[i] = 0.f;
        const int b = blk * 4 + (tid >> 7), k = tid & 127;
        xT[(size_t)k * B + b] = x[(size_t)b * T * IN + k];
    }
    grid.sync();

    for (int t = 0; t < T; ++t) {
        const float* xTc = xT + (t & 1) * (IN * B);
        const float* h1p = h1buf + (t & 1) * (H1 * B);
        float*       h1c = h1buf + ((t + 1) & 1) * (H1 * B);
        const float* h2p = h2buf + (t & 1) * (H2 * B);
        float*       h2c = h2buf + ((t + 1) & 1) * (H2 * B);
        const float* h3p = h3buf + (t & 1) * (H3 * B);
        float*       h3c = h3buf + ((t + 1) & 1) * (H3 * B);

        // ================= Phase 1: head(t-1) + L1(t) =================
        stage256(xTc + bgq * 256, sact0);   // tile 0 in flight ASAP

        if (blk < 4 && t > 0) {
            if (tid < H3) {
                float s = 0.f, sq = 0.f;
                #pragma unroll
                for (int p = 0; p < 4; ++p) {
                    const float4 q = *(const float4*)&st3[tid * 16 + p * 4];
                    s += q.x + q.z; sq += q.y + q.w;
                }
                const float mu  = s * (1.f / B);
                const float var = sq * (1.f / B) - mu * mu;
                const float a   = g3v[tid] * rsqrtf(var + EPS);
                s_a3[tid] = a; s_d3[tid] = b3v[tid] - mu * a;
            }
            __syncthreads();
            if (tid < 256) {
                const int b = blk * 256 + tid;
                float y0 = bl[0], y1 = bl[1];
                #pragma unroll
                for (int ch = 0; ch < H3; ++ch) {
                    const float z = s_a3[ch] * h3p[(size_t)ch * B + b] + s_d3[ch];
                    y0 += Wl[ch] * z; y1 += Wl[H3 + ch] * z;
                }
                y0 = fmaxf(y0, 0.f); y1 = fmaxf(y1, 0.f);
                const float u0 = Wl2[0] * y0 + Wl2[1] * y1 + bl2[0];
                const float u1 = Wl2[2] * y0 + Wl2[3] * y1 + bl2[1];
                const float m  = fmaxf(u0, u1);
                const float e0 = __expf(u0 - m), e1 = __expf(u1 - m);
                const float inv = 1.f / (e0 + e1);
                out[((size_t)b * T + (t - 1)) * 2 + 0] = e0 * inv;
                out[((size_t)b * T + (t - 1)) * 2 + 1] = e1 * inv;
            }
        }
        __syncthreads();   // tile 0 staged

        {
            float ar0[4] = {0.f, 0.f, 0.f, 0.f};
            float ar1[4] = {0.f, 0.f, 0.f, 0.f};
            const float* wb = &s_w1[(chl * 4) * K1];
            for (int i = 0; i < 12; ++i) {
                float* cur = (i & 1) ? sact1 : sact0;
                float* nxt = (i & 1) ? sact0 : sact1;
                if (i + 1 < 12) {
                    const float* s = (i + 1 < 4)
                        ? (xTc + (size_t)(i + 1) * TK * B + bgq * 256)
                        : (h1p + (size_t)(i + 1 - 4) * TK * B + bgq * 256);
                    stage256(s, nxt);
                }
                const int k0 = i * TK;
                P12_TILE(wb, K1, k0, cur)
                __syncthreads();
            }
            const int ch = ch0 + chl;
            float2 cc = *(float2*)&c1[(size_t)ch * B + bposA];
            const float b0 = s_b1[chl * 4 + 0], b1 = s_b1[chl * 4 + 1];
            const float b2 = s_b1[chl * 4 + 2], b3 = s_b1[chl * 4 + 3];
            const float hn0 = lstm_point(ar0[0] + b0, ar0[1] + b1, ar0[2] + b2, ar0[3] + b3, cc.x);
            const float hn1 = lstm_point(ar1[0] + b0, ar1[1] + b1, ar1[2] + b2, ar1[3] + b3, cc.y);
            *(float2*)&c1[(size_t)ch * B + bposA]  = cc;
            *(float2*)&h1c[(size_t)ch * B + bposA] = make_float2(hn0, hn1);
            float psum = hn0 + hn1, psq = hn0 * hn0 + hn1 * hn1;
            #pragma unroll
            for (int off = 32; off > 0; off >>= 1) {
                psum += __shfl_xor(psum, off, 64);
                psq  += __shfl_xor(psq,  off, 64);
            }
            if ((tid & 63) == 0) { s_red[wv * 2 + 0] = psum; s_red[wv * 2 + 1] = psq; }
        }
        __syncthreads();
        if (tid < 4) {
            st1[((ch0 + tid) * 4 + bgq) * 2 + 0] = s_red[(2 * tid) * 2 + 0] + s_red[(2 * tid + 1) * 2 + 0];
            st1[((ch0 + tid) * 4 + bgq) * 2 + 1] = s_red[(2 * tid) * 2 + 1] + s_red[(2 * tid + 1) * 2 + 1];
        }
        grid.sync();

        // ================= Phase 2: BN1 (folded) + L2(t) =================
        stage256(h1c + bgq * 256, sact0);   // tile 0 (h1c k=0..31)
        if (tid < H1) {
            const float4 p0 = *(const float4*)&st1[tid * 8];
            const float4 p1 = *(const float4*)&st1[tid * 8 + 4];
            const float s  = p0.x + p0.z + p1.x + p1.z;
            const float sq = p0.y + p0.w + p1.y + p1.w;
            const float mu  = s * (1.f / B);
            const float var = sq * (1.f / B) - mu * mu;
            const float a   = g1v[tid] * rsqrtf(var + EPS);
            s_a[tid] = a; s_d[tid] = b1v[tid] - mu * a;
        }
        __syncthreads();   // tile 0 + s_a/s_d ready
        {
            float ar0[4] = {0.f, 0.f, 0.f, 0.f};
            float ar1[4] = {0.f, 0.f, 0.f, 0.f};
            const float* wb = &s_w2[(chl * 4) * K2];
            for (int i = 0; i < 16; ++i) {
                float* cur = (i & 1) ? sact1 : sact0;
                float* nxt = (i & 1) ? sact0 : sact1;
                if (i + 1 < 16) {
                    const float* s = (i + 1 < 8)
                        ? (h1c + (size_t)(i + 1) * TK * B + bgq * 256)
                        : (h2p + (size_t)(i + 1 - 8) * TK * B + bgq * 256);
                    stage256(s, nxt);
                }
                const int k0 = i * TK;
                if (i < 8) { P2F_TILE(wb, K2, k0, cur) }
                else       { P12_TILE(wb, K2, k0, cur) }
                __syncthreads();
            }
            const int ch = ch0 + chl;
            float2 cc = *(float2*)&c2[(size_t)ch * B + bposA];
            const float b0 = s_b2[chl * 4 + 0], b1 = s_b2[chl * 4 + 1];
            const float b2_ = s_b2[chl * 4 + 2], b3 = s_b2[chl * 4 + 3];
            const float hn0 = lstm_point(ar0[0] + b0, ar0[1] + b1, ar0[2] + b2_, ar0[3] + b3, cc.x);
            const float hn1 = lstm_point(ar1[0] + b0, ar1[1] + b1, ar1[2] + b2_, ar1[3] + b3, cc.y);
            *(float2*)&c2[(size_t)ch * B + bposA]  = cc;
            *(float2*)&h2c[(size_t)ch * B + bposA] = make_float2(hn0, hn1);
            float psum = hn0 + hn1, psq = hn0 * hn0 + hn1 * hn1;
            #pragma unroll
            for (int off = 32; off > 0; off >>= 1) {
                psum += __shfl_xor(psum, off, 64);
                psq  += __shfl_xor(psq,  off, 64);
            }
            if ((tid & 63) == 0) { s_red[wv * 2 + 0] = psum; s_red[wv * 2 + 1] = psq; }
        }
        __syncthreads();
        if (tid < 4) {
            st2[((ch0 + tid) * 4 + bgq) * 2 + 0] = s_red[(2 * tid) * 2 + 0] + s_red[(2 * tid + 1) * 2 + 0];
            st2[((ch0 + tid) * 4 + bgq) * 2 + 1] = s_red[(2 * tid) * 2 + 1] + s_red[(2 * tid + 1) * 2 + 1];
        }
        grid.sync();

        // ================= Phase 3: BN2 (folded) + L3(t) + xT staging =================
        stage128(h2c + bg3 * 128, sact0);   // tile 0 (h2c k=0..31)
        if (tid < H2) {
            const float4 p0 = *(const float4*)&st2[tid * 8];
            const float4 p1 = *(const float4*)&st2[tid * 8 + 4];
            const float s  = p0.x + p0.z + p1.x + p1.z;
            const float sq = p0.y + p0.w + p1.y + p1.w;
            const float mu  = s * (1.f / B);
            const float var = sq * (1.f / B) - mu * mu;
            const float a   = g2v[tid] * rsqrtf(var + EPS);
            s_a[tid] = a; s_d[tid] = b2v[tid] - mu * a;
        }
        if (tid >= 256 && t + 1 < T) {
            const int tt = tid - 256;
            const int b  = blk * 4 + (tt >> 6);
            const int kk = (tt & 63) * 2;
            const float2 v = *(const float2*)&x[((size_t)b * T + (t + 1)) * IN + kk];
            float* xTn = xT + ((t + 1) & 1) * (IN * B);
            xTn[(size_t)kk * B + b]       = v.x;
            xTn[(size_t)(kk + 1) * B + b] = v.y;
        }
        __syncthreads();   // tile 0 + s_a/s_d ready
        {
            float a0 = 0.f, a1 = 0.f, a2 = 0.f, a3 = 0.f;
            for (int i = 0; i < 9; ++i) {
                float* cur = (i & 1) ? sact1 : sact0;
                float* nxt = (i & 1) ? sact0 : sact1;
                if (i + 1 < 9) {
                    const float* s = (i + 1 < 8)
                        ? (h2c + (size_t)(i + 1) * TK * B + bg3 * 128)
                        : (h3p + bg3 * 128);
                    stage128(s, nxt);
                }
                if (tid < 128) {
                    if (i < 8) {
                        const int k0 = i * TK;
                        #pragma unroll
                        for (int kk = 0; kk < TK; kk += 4) {
                            const float4 w0 = *(const float4*)&s_w3[0 * K3 + k0 + kk];
                            const float4 w1 = *(const float4*)&s_w3[1 * K3 + k0 + kk];
                            const float4 w2 = *(const float4*)&s_w3[2 * K3 + k0 + kk];
                            const float4 w3 = *(const float4*)&s_w3[3 * K3 + k0 + kk];
                            const float4 av = *(const float4*)&s_a[k0 + kk];
                            const float4 dv = *(const float4*)&s_d[k0 + kk];
                            float z0 = cur[(kk + 0) * 128 + tid];
                            float z1 = cur[(kk + 1) * 128 + tid];
                            float z2 = cur[(kk + 2) * 128 + tid];
                            float z3 = cur[(kk + 3) * 128 + tid];
                            z0 = av.x * z0 + dv.x; z1 = av.y * z1 + dv.y;
                            z2 = av.z * z2 + dv.z; z3 = av.w * z3 + dv.w;
                            a0 += z0*w0.x + z1*w0.y + z2*w0.z + z3*w0.w;
                            a1 += z0*w1.x + z1*w1.y + z2*w1.z + z3*w1.w;
                            a2 += z0*w2.x + z1*w2.y + z2*w2.z + z3*w2.w;
                            a3 += z0*w3.x + z1*w3.y + z2*w3.z + z3*w3.w;
                        }
                    } else {
                        #pragma unroll
                        for (int kk = 0; kk < TK; kk += 4) {
                            const float4 w0 = *(const float4*)&s_w3[0 * K3 + H2 + kk];
                            const float4 w1 = *(const float4*)&s_w3[1 * K3 + H2 + kk];
                            const float4 w2 = *(const float4*)&s_w3[2 * K3 + H2 + kk];
                            const float4 w3 = *(const float4*)&s_w3[3 * K3 + H2 + kk];
                            const float z0 = cur[(kk + 0) * 128 + tid];
                            const float z1 = cur[(kk + 1) * 128 + tid];
                            const float z2 = cur[(kk + 2) * 128 + tid];
                            const float z3 = cur[(kk + 3) * 128 + tid];
                            a0 += z0*w0.x + z1*w0.y + z2*w0.z + z3*w0.w;
                            a1 += z0*w1.x + z1*w1.y + z2*w1.z + z3*w1.w;
                            a2 += z0*w2.x + z1*w2.y + z2*w2.z + z3*w2.w;
                            a3 += z0*w3.x + z1*w3.y + z2*w3.z + z3*w3.w;
                        }
                    }
                }
                __syncthreads();
            }
            if (tid < 128) {
                const int b = bg3 * 128 + tid;
                float cc = c3[(size_t)ch3 * B + b];
                const float hn = lstm_point(a0 + s_b3[0], a1 + s_b3[1], a2 + s_b3[2], a3 + s_b3[3], cc);
                c3[(size_t)ch3 * B + b]  = cc;
                h3c[(size_t)ch3 * B + b] = hn;
                float psum = hn, psq = hn * hn;
                #pragma unroll
                for (int off = 32; off > 0; off >>= 1) {
                    psum += __shfl_xor(psum, off, 64);
                    psq  += __shfl_xor(psq,  off, 64);
                }
                if ((tid & 63) == 0) { s_red[(tid >> 6) * 2 + 0] = psum; s_red[(tid >> 6) * 2 + 1] = psq; }
            }
        }
        __syncthreads();
        if (tid == 0) {
            st3[(ch3 * 8 + bg3) * 2 + 0] = s_red[0] + s_red[2];
            st3[(ch3 * 8 + bg3) * 2 + 1] = s_red[1] + s_red[3];
        }
        grid.sync();
    }

    // final head for t = T-1
    if (blk < 4) {
        const float* h3s = h3buf + (T & 1) * (H3 * B);
        if (tid < H3) {
            float s = 0.f, sq = 0.f;
            #pragma unroll
            for (int p = 0; p < 4; ++p) {
                const float4 q = *(const float4*)&st3[tid * 16 + p * 4];
                s += q.x + q.z; sq += q.y + q.w;
            }
            const float mu  = s * (1.f / B);
            const float var = sq * (1.f / B) - mu * mu;
            const float a   = g3v[tid] * rsqrtf(var + EPS);
            s_a3[tid] = a; s_d3[tid] = b3v[tid] - mu * a;
        }
        __syncthreads();
        if (tid < 256) {
            const int b = blk * 256 + tid;
            float y0 = bl[0], y1 = bl[1];
            #pragma unroll
            for (int ch = 0; ch < H3; ++ch) {
                const float z = s_a3[ch] * h3s[(size_t)ch * B + b] + s_d3[ch];
                y0 += Wl[ch] * z; y1 += Wl[H3 + ch] * z;
            }
            y0 = fmaxf(y0, 0.f); y1 = fmaxf(y1, 0.f);
            const float u0 = Wl2[0] * y0 + Wl2[1] * y1 + bl2[0];
            const float u1 = Wl2[2] * y0 + Wl2[3] * y1 + bl2[1];
            const float m  = fmaxf(u0, u1);
            const float e0 = __expf(u0 - m), e1 = __expf(u1 - m);
            const float inv = 1.f / (e0 + e1);
            out[((size_t)b * T + (T - 1)) * 2 + 0] = e0 * inv;
            out[((size_t)b * T + (T - 1)) * 2 + 1] = e1 * inv;
        }
    }
}

extern "C" void kernel_launch(void* const* d_in, const int* in_sizes, int n_in,
                              void* d_out, int out_size, void* d_ws, size_t ws_size,
                              hipStream_t stream) {
    const float* x    = (const float*)d_in[0];
    const float* Wih1 = (const float*)d_in[1];
    const float* Whh1 = (const float*)d_in[2];
    const float* bih1 = (const float*)d_in[3];
    const float* bhh1 = (const float*)d_in[4];
    const float* g1   = (const float*)d_in[5];
    const float* b1   = (const float*)d_in[6];
    const float* Wih2 = (const float*)d_in[7];
    const float* Whh2 = (const float*)d_in[8];
    const float* bih2 = (const float*)d_in[9];
    const float* bhh2 = (const float*)d_in[10];
    const float* g2   = (const float*)d_in[11];
    const float* b2   = (const float*)d_in[12];
    const float* Wih3 = (const float*)d_in[13];
    const float* Whh3 = (const float*)d_in[14];
    const float* bih3 = (const float*)d_in[15];
    const float* bhh3 = (const float*)d_in[16];
    const float* g3   = (const float*)d_in[17];
    const float* b3   = (const float*)d_in[18];
    const float* Wl   = (const float*)d_in[19];
    const float* bl   = (const float*)d_in[20];
    const float* Wl2  = (const float*)d_in[21];
    const float* bl2  = (const float*)d_in[22];
    float* out = (float*)d_out;
    float* ws  = (float*)d_ws;

    const int dyn_lds = 2 * TK * 256 * sizeof(float);   // 65536
    hipFuncSetAttribute((const void*)cryptonet_kernel,
                        hipFuncAttributeMaxDynamicSharedMemorySize, dyn_lds);

    void* args[] = { &x, &Wih1, &Whh1, &bih1, &bhh1, &g1, &b1,
                     &Wih2, &Whh2, &bih2, &bhh2, &g2, &b2,
                     &Wih3, &Whh3, &bih3, &bhh3, &g3, &b3,
                     &Wl, &bl, &Wl2, &bl2, &out, &ws };
    hipLaunchCooperativeKernel((const void*)cryptonet_kernel, dim3(NBLK), dim3(NTHR),
                               args, dyn_lds, stream);
}